// Round 1
// baseline (214.891 us; speedup 1.0000x reference)
//
#include <hip/hip_runtime.h>

#define T_TOKENS 8192
#define K_DIM    4096
#define NEXP     64
#define TM       4              // tokens per wave
#define WAVES    8              // waves per block
#define TOK_BLK  (TM * WAVES)   // 32 tokens per block
#define KC       128            // k per LDS chunk
#define KC4      (KC / 4)       // 32 float4 per expert per chunk
#define NCHUNK   (K_DIM / KC)   // 32 chunks

static_assert(T_TOKENS % TOK_BLK == 0, "token tiling");
static_assert(K_DIM % KC == 0, "k tiling");

__global__ __launch_bounds__(512, 2) void router_fused(
    const float* __restrict__ x,
    const float* __restrict__ W,
    float* __restrict__ out)
{
    // double-buffered W^T chunk: [k4local][expert] float4, 2 x 32 KiB
    __shared__ float4 sw[2][KC4 * NEXP];

    const int tid  = threadIdx.x;          // 0..511
    const int lane = tid & 63;             // expert id for compute
    const int wv   = __builtin_amdgcn_readfirstlane(tid >> 6);   // wave 0..7 (uniform)
    const int t0   = blockIdx.x * TOK_BLK + wv * TM;

    // staging role: thread (e_s, ks) loads W[e_s][4*(c*32 + r*8 + ks) .. +3]
    const int e_s = tid >> 3;              // 0..63
    const int ks  = tid & 7;               // 0..7
    const float4* W4 = (const float4*)W;   // [NEXP][K_DIM/4]
    const size_t wbase = (size_t)e_s * (K_DIM / 4) + ks;

    // wave-uniform x row pointers -> scalar loads
    const float4* xr0 = (const float4*)(x + (size_t)(t0 + 0) * K_DIM);
    const float4* xr1 = (const float4*)(x + (size_t)(t0 + 1) * K_DIM);
    const float4* xr2 = (const float4*)(x + (size_t)(t0 + 2) * K_DIM);
    const float4* xr3 = (const float4*)(x + (size_t)(t0 + 3) * K_DIM);

    float4 acc0 = {0.f,0.f,0.f,0.f}, acc1 = {0.f,0.f,0.f,0.f};
    float4 acc2 = {0.f,0.f,0.f,0.f}, acc3 = {0.f,0.f,0.f,0.f};

    // prologue: load chunk 0 into registers
    float4 st[4];
#pragma unroll
    for (int r = 0; r < 4; ++r)
        st[r] = W4[wbase + r * 8];

    for (int c = 0; c < NCHUNK; ++c) {
        float4* buf = sw[c & 1];
        // commit staged chunk c to LDS (transpose-on-stage: slot [k4][e])
#pragma unroll
        for (int r = 0; r < 4; ++r)
            buf[(r * 8 + ks) * NEXP + e_s] = st[r];
        __syncthreads();

        // prefetch chunk c+1 from global (latency hides under compute below)
        if (c + 1 < NCHUNK) {
#pragma unroll
            for (int r = 0; r < 4; ++r)
                st[r] = W4[wbase + (size_t)(c + 1) * KC4 + r * 8];
        }

        const int kbase = c * KC4;
#pragma unroll 8
        for (int i = 0; i < KC4; ++i) {
            float4 w  = buf[i * NEXP + lane];      // ds_read_b128, contiguous
            float4 a0 = xr0[kbase + i];            // wave-uniform -> s_load
            float4 a1 = xr1[kbase + i];
            float4 a2 = xr2[kbase + i];
            float4 a3 = xr3[kbase + i];
            acc0.x += a0.x * w.x; acc0.y += a0.y * w.y; acc0.z += a0.z * w.z; acc0.w += a0.w * w.w;
            acc1.x += a1.x * w.x; acc1.y += a1.y * w.y; acc1.z += a1.z * w.z; acc1.w += a1.w * w.w;
            acc2.x += a2.x * w.x; acc2.y += a2.y * w.y; acc2.z += a2.z * w.z; acc2.w += a2.w * w.w;
            acc3.x += a3.x * w.x; acc3.y += a3.y * w.y; acc3.z += a3.z * w.z; acc3.w += a3.w * w.w;
        }
        __syncthreads();
    }

    float lg[TM];
    lg[0] = (acc0.x + acc0.y) + (acc0.z + acc0.w);
    lg[1] = (acc1.x + acc1.y) + (acc1.z + acc1.w);
    lg[2] = (acc2.x + acc2.y) + (acc2.z + acc2.w);
    lg[3] = (acc3.x + acc3.y) + (acc3.z + acc3.w);

    float* out_w = out;                                  // [8192]
    float* out_i = out + T_TOKENS;                       // [8192] (indices as float)
    float* out_s = out + 2 * T_TOKENS;                   // [8192][64]
    float* out_c = out + 2 * T_TOKENS + T_TOKENS * NEXP; // [64]

#pragma unroll
    for (int t = 0; t < TM; ++t) {
        float l = lg[t];
        // wave max over 64 lanes
        float m = l;
#pragma unroll
        for (int off = 32; off > 0; off >>= 1)
            m = fmaxf(m, __shfl_xor(m, off));
        float p = expf(l - m);
        // wave sum
        float s = p;
#pragma unroll
        for (int off = 32; off > 0; off >>= 1)
            s += __shfl_xor(s, off);
        float sc = p / s;                 // softmax score for (token, lane-expert)
        // argmax over computed scores, first-index tie-break (matches np/jnp)
        float bv = sc; int bi = lane;
#pragma unroll
        for (int off = 32; off > 0; off >>= 1) {
            float ov = __shfl_xor(bv, off);
            int   oi = __shfl_xor(bi, off);
            if (ov > bv || (ov == bv && oi < bi)) { bv = ov; bi = oi; }
        }
        out_s[(size_t)(t0 + t) * NEXP + lane] = sc;
        if (lane == 0) {
            out_w[t0 + t] = bv;
            out_i[t0 + t] = (float)bi;
            atomicAdd(&out_c[bi], 1.0f);
        }
    }
}

extern "C" void kernel_launch(void* const* d_in, const int* in_sizes, int n_in,
                              void* d_out, int out_size, void* d_ws, size_t ws_size,
                              hipStream_t stream)
{
    const float* x = (const float*)d_in[0];
    const float* W = (const float*)d_in[1];
    float* out = (float*)d_out;

    // zero routing_counts region (atomically accumulated each call)
    hipMemsetAsync(out + 2 * T_TOKENS + T_TOKENS * NEXP, 0, NEXP * sizeof(float), stream);

    router_fused<<<T_TOKENS / TOK_BLK, 512, 0, stream>>>(x, W, out);
}

// Round 2
// 150.072 us; speedup vs baseline: 1.4319x; 1.4319x over previous
//
#include <hip/hip_runtime.h>

#define T_TOKENS 8192
#define K_DIM    4096
#define NEXP     64
#define TOK_TILE 256            // tokens per block
#define KC       32             // k elems per LDS chunk
#define KC4      8              // float4 per row per chunk
#define TM       4              // tokens per thread (lane + 64*tm)
#define TE       8              // experts per wave (wave-uniform)

// ---------------- kernel 1: partial logits (split-K GEMM M=8192 N=64) ----------
// grid = 32 * S blocks, 512 threads (8 waves). Block: 256 tokens x 64 experts x KS.
// x tile staged in LDS, XOR-swizzled [k4][token^k4] float4 layout (64 KiB dbuf,
// conflict-free b128 reads AND writes). W read wave-uniform -> scalar loads.
__global__ __launch_bounds__(512, 4) void router_gemv(
    const float* __restrict__ x,
    const float* __restrict__ W,
    float* __restrict__ P,      // [S][8192][64] partial logits
    int KS)                     // k-extent per slice (4096/S)
{
    __shared__ float4 xs[2][KC4][TOK_TILE];   // exactly 65536 B

    const int tid  = threadIdx.x;
    const int lane = tid & 63;
    const int wv   = __builtin_amdgcn_readfirstlane(tid >> 6);  // wave 0..7
    const int tile  = blockIdx.x & 31;
    const int slice = blockIdx.x >> 5;
    const int t0 = tile * TOK_TILE;
    const int k0 = slice * KS;
    const int nchunk = KS / KC;

    // staging role: thread (sr, sk) loads rows sr+64m, float4-col sk of the chunk
    const int sr = tid >> 3;     // 0..63
    const int sk = tid & 7;      // 0..7
    const float4* x4 = (const float4*)x;                 // [8192][1024]
    const size_t xbase = ((size_t)(t0 + sr) << 10) + (size_t)(k0 >> 2) + sk;

    const int e0 = wv * TE;      // wave-uniform expert base
    const float* __restrict__ Wp = W;

    float acc[TM][TE];
#pragma unroll
    for (int tm = 0; tm < TM; ++tm)
#pragma unroll
        for (int j = 0; j < TE; ++j) acc[tm][j] = 0.f;

    // prologue: stage chunk 0 into regs
    float4 st[4];
#pragma unroll
    for (int m = 0; m < 4; ++m)
        st[m] = x4[xbase + ((size_t)m << 16)];           // 64 rows * 1024 f4

    for (int c = 0; c < nchunk; ++c) {
        const int b = c & 1;
        // commit staged chunk c (XOR-swizzled, conflict-free b128 writes)
#pragma unroll
        for (int m = 0; m < 4; ++m)
            xs[b][sk][(sr ^ sk) + (m << 6)] = st[m];
        __syncthreads();

        // prefetch chunk c+1 (latency hides under the 1024-FMA compute below)
        if (c + 1 < nchunk) {
#pragma unroll
            for (int m = 0; m < 4; ++m)
                st[m] = x4[xbase + (size_t)(c + 1) * KC4 + ((size_t)m << 16)];
        }

        const int kg = k0 + c * KC;                      // global k of chunk start
#pragma unroll
        for (int k4 = 0; k4 < KC4; ++k4) {
            float4 xv[TM];
            const float4* xr = &xs[b][k4][lane ^ k4];
#pragma unroll
            for (int tm = 0; tm < TM; ++tm) xv[tm] = xr[tm << 6];
#pragma unroll
            for (int j = 0; j < TE; ++j) {
                // wave-uniform address -> s_load_dwordx4 (scalar path)
                float4 wj = *(const float4*)(Wp + (size_t)(e0 + j) * K_DIM + kg + (k4 << 2));
#pragma unroll
                for (int tm = 0; tm < TM; ++tm) {
                    float a = acc[tm][j];
                    a = __builtin_fmaf(xv[tm].x, wj.x, a);
                    a = __builtin_fmaf(xv[tm].y, wj.y, a);
                    a = __builtin_fmaf(xv[tm].z, wj.z, a);
                    a = __builtin_fmaf(xv[tm].w, wj.w, a);
                    acc[tm][j] = a;
                }
            }
        }
        __syncthreads();
    }

    // write partial logits: P[slice][t][e0..e0+7] as two float4
    float4* P4 = (float4*)P;
    const size_t pbase = (size_t)slice * T_TOKENS * (NEXP / 4);
#pragma unroll
    for (int tm = 0; tm < TM; ++tm) {
        const int t = t0 + lane + (tm << 6);
        float4 lo = { acc[tm][0], acc[tm][1], acc[tm][2], acc[tm][3] };
        float4 hi = { acc[tm][4], acc[tm][5], acc[tm][6], acc[tm][7] };
        P4[pbase + (size_t)t * (NEXP / 4) + wv * 2 + 0] = lo;
        P4[pbase + (size_t)t * (NEXP / 4) + wv * 2 + 1] = hi;
    }
}

// ---------------- kernel 2: reduce slices + softmax + argmax + bincount --------
__global__ __launch_bounds__(256) void router_finish(
    const float* __restrict__ P, float* __restrict__ out, int S)
{
    const int lane = threadIdx.x & 63;   // expert
    const int wv   = threadIdx.x >> 6;
    const int t    = blockIdx.x * 4 + wv;

    float l = 0.f;
    for (int s = 0; s < S; ++s)
        l += P[((size_t)s * T_TOKENS + t) * NEXP + lane];

    float* out_w = out;
    float* out_i = out + T_TOKENS;
    float* out_s = out + 2 * T_TOKENS;
    float* out_c = out + 2 * T_TOKENS + (size_t)T_TOKENS * NEXP;

    float m = l;
#pragma unroll
    for (int off = 32; off > 0; off >>= 1)
        m = fmaxf(m, __shfl_xor(m, off));
    float p = expf(l - m);
    float s = p;
#pragma unroll
    for (int off = 32; off > 0; off >>= 1)
        s += __shfl_xor(s, off);
    float sc = p / s;

    float bv = sc; int bi = lane;
#pragma unroll
    for (int off = 32; off > 0; off >>= 1) {
        float ov = __shfl_xor(bv, off);
        int   oi = __shfl_xor(bi, off);
        if (ov > bv || (ov == bv && oi < bi)) { bv = ov; bi = oi; }
    }
    out_s[(size_t)t * NEXP + lane] = sc;
    if (lane == 0) {
        out_w[t] = bv;
        out_i[t] = (float)bi;
        atomicAdd(&out_c[bi], 1.0f);
    }
}

extern "C" void kernel_launch(void* const* d_in, const int* in_sizes, int n_in,
                              void* d_out, int out_size, void* d_ws, size_t ws_size,
                              hipStream_t stream)
{
    const float* x = (const float*)d_in[0];
    const float* W = (const float*)d_in[1];
    float* out = (float*)d_out;
    float* out_s = out + 2 * T_TOKENS;

    const size_t per_slice = (size_t)T_TOKENS * NEXP * sizeof(float);  // 2 MiB
    int S;
    if      (ws_size >= 16 * per_slice) S = 16;
    else if (ws_size >=  8 * per_slice) S = 8;
    else if (ws_size >=  4 * per_slice) S = 4;
    else if (ws_size >=  2 * per_slice) S = 2;
    else                                S = 1;
    float* Pbuf = (S == 1 && ws_size < per_slice) ? out_s : (float*)d_ws;

    // zero routing_counts (atomically accumulated in kernel 2)
    hipMemsetAsync(out + 2 * T_TOKENS + (size_t)T_TOKENS * NEXP, 0,
                   NEXP * sizeof(float), stream);

    router_gemv<<<32 * S, 512, 0, stream>>>(x, W, Pbuf, K_DIM / S);
    router_finish<<<T_TOKENS / 4, 256, 0, stream>>>(Pbuf, out, S);
}

// Round 3
// 97.699 us; speedup vs baseline: 2.1995x; 1.5361x over previous
//
#include <hip/hip_runtime.h>
#include <stdint.h>

#define T_TOKENS 8192
#define K_DIM    4096
#define NEXP     64
#define TB       128            // tokens per gemm block (8 waves x 16)
#define KC       32             // k per chunk = one MFMA k-step

typedef short bf16x8 __attribute__((ext_vector_type(8)));
typedef float f32x4  __attribute__((ext_vector_type(4)));

// float -> bf16 (RNE) bit tricks; residual v - bf2f(f2bf(v)) is exact in fp32
__device__ __forceinline__ uint32_t f2bf(float v) {
    uint32_t u = __builtin_bit_cast(uint32_t, v);
    return (u + 0x7fffu + ((u >> 16) & 1u)) >> 16;
}
__device__ __forceinline__ float bf2f(uint32_t b) {
    return __builtin_bit_cast(float, b << 16);
}

// ---------- kernel 0: W [64][4096] fp32 -> fragment-ordered bf16 terms -------
// Wf layout (float4 = bf16x8 units): [kstep 128][etile 4][term 3][lane 64]
// B-frag content: lane l, elem j = W[etile*16 + (l&15)][kstep*32 + (l>>4)*8 + j]
__global__ void wpack(const float* __restrict__ W, float4* __restrict__ Wf) {
    const int l     = threadIdx.x;       // 0..63
    const int kstep = blockIdx.x;        // 0..127
    const int etile = blockIdx.y;        // 0..3
    const int e = etile * 16 + (l & 15);
    const int k = kstep * 32 + (l >> 4) * 8;
    const float* src = W + (size_t)e * K_DIM + k;
    bf16x8 h, l1, l2;
#pragma unroll
    for (int j = 0; j < 8; ++j) {
        float v = src[j];
        uint32_t hb = f2bf(v); float r  = v - bf2f(hb);
        uint32_t lb = f2bf(r); float r2 = r - bf2f(lb);
        uint32_t qb = f2bf(r2);
        h[j] = (short)hb; l1[j] = (short)lb; l2[j] = (short)qb;
    }
    const size_t base = ((size_t)(kstep * 4 + etile) * 3) * 64 + l;
    Wf[base]       = __builtin_bit_cast(float4, h);
    Wf[base + 64]  = __builtin_bit_cast(float4, l1);
    Wf[base + 128] = __builtin_bit_cast(float4, l2);
}

// ---------- kernel 1: split-K GEMM, logits partials via 6x bf16 MFMA ---------
__global__ __launch_bounds__(512, 4) void gemm_mfma(
    const float*  __restrict__ x,
    const float4* __restrict__ Wf,
    float* __restrict__ P,          // [S][8192][64]
    int KS)                         // k per slice
{
    __shared__ float4 xbuf[2][TB * 8];   // 128 rows x 32 fp32 (8 f4, XOR-swz) x2 = 32 KB
    __shared__ float4 bbuf[2][12 * 64];  // [etile][term][lane] x2 = 24 KB

    const int tid  = threadIdx.x;
    const int l    = tid & 63;
    const int wv   = __builtin_amdgcn_readfirstlane(tid >> 6);  // token-16 tile
    const int t0   = blockIdx.x * TB;
    const int slice = blockIdx.y;
    const int k0   = slice * KS;
    const int nchunk = KS / KC;

    // x staging role: thread covers rows {tid>>3, tid>>3+64}, f4-slot tid&7
    const int srow = tid >> 3;
    const int sslot = tid & 7;
    const size_t xg0 = (size_t)(t0 + srow) * (K_DIM / 4) + (size_t)(k0 >> 2) + sslot;
    const size_t xg1 = xg0 + (size_t)64 * (K_DIM / 4);
    // B staging: slots tid and tid+512 (tid<256); chunk = 768 f4 = 12 KB
    const size_t bg0 = ((size_t)(k0 / 32)) * 768;

    f32x4 acc[4];
#pragma unroll
    for (int et = 0; et < 4; ++et) acc[et] = (f32x4){0.f, 0.f, 0.f, 0.f};

    // prologue: stage chunk 0 into regs
    float4 xr0 = ((const float4*)x)[xg0];
    float4 xr1 = ((const float4*)x)[xg1];
    float4 br0 = Wf[bg0 + tid];
    float4 br1 = (tid < 256) ? Wf[bg0 + tid + 512] : (float4){0,0,0,0};

    // A-read address (swizzled): row = wv*16 + (l&15), slots (l>>4)*2, +1
    const int arow = wv * 16 + (l & 15);
    const int as0 = arow * 8 + (((l >> 4) * 2)     ^ (arow & 7));
    const int as1 = arow * 8 + (((l >> 4) * 2 + 1) ^ (arow & 7));

    for (int c = 0; c < nchunk; ++c) {
        const int b = c & 1;
        // commit staged chunk c (x swizzled, B linear)
        xbuf[b][srow * 8        + (sslot ^ (srow & 7))]        = xr0;
        xbuf[b][(srow + 64) * 8 + (sslot ^ ((srow + 64) & 7))] = xr1;
        bbuf[b][tid] = br0;
        if (tid < 256) bbuf[b][tid + 512] = br1;
        __syncthreads();

        // prefetch chunk c+1
        if (c + 1 < nchunk) {
            xr0 = ((const float4*)x)[xg0 + (c + 1) * 8];
            xr1 = ((const float4*)x)[xg1 + (c + 1) * 8];
            br0 = Wf[bg0 + (size_t)(c + 1) * 768 + tid];
            if (tid < 256) br1 = Wf[bg0 + (size_t)(c + 1) * 768 + tid + 512];
        }

        // A fragments: 8 fp32 -> 3 bf16 terms
        float4 a0 = xbuf[b][as0];
        float4 a1 = xbuf[b][as1];
        float av[8] = {a0.x, a0.y, a0.z, a0.w, a1.x, a1.y, a1.z, a1.w};
        bf16x8 xh, xl, xq;
#pragma unroll
        for (int j = 0; j < 8; ++j) {
            float v = av[j];
            uint32_t hb = f2bf(v); float r  = v - bf2f(hb);
            uint32_t lb = f2bf(r); float r2 = r - bf2f(lb);
            uint32_t qb = f2bf(r2);
            xh[j] = (short)hb; xl[j] = (short)lb; xq[j] = (short)qb;
        }

#pragma unroll
        for (int et = 0; et < 4; ++et) {
            const float4* bp = &bbuf[b][et * 3 * 64 + l];
            bf16x8 wh = __builtin_bit_cast(bf16x8, bp[0]);
            bf16x8 wl = __builtin_bit_cast(bf16x8, bp[64]);
            bf16x8 wq = __builtin_bit_cast(bf16x8, bp[128]);
            acc[et] = __builtin_amdgcn_mfma_f32_16x16x32_bf16(xh, wh, acc[et], 0, 0, 0);
            acc[et] = __builtin_amdgcn_mfma_f32_16x16x32_bf16(xh, wl, acc[et], 0, 0, 0);
            acc[et] = __builtin_amdgcn_mfma_f32_16x16x32_bf16(xh, wq, acc[et], 0, 0, 0);
            acc[et] = __builtin_amdgcn_mfma_f32_16x16x32_bf16(xl, wh, acc[et], 0, 0, 0);
            acc[et] = __builtin_amdgcn_mfma_f32_16x16x32_bf16(xl, wl, acc[et], 0, 0, 0);
            acc[et] = __builtin_amdgcn_mfma_f32_16x16x32_bf16(xq, wh, acc[et], 0, 0, 0);
        }
        __syncthreads();
    }

    // epilogue: C/D map col=lane&15 (expert), row=(lane>>4)*4+i (token)
    float* Pp = P + (size_t)slice * T_TOKENS * NEXP;
#pragma unroll
    for (int et = 0; et < 4; ++et) {
#pragma unroll
        for (int i = 0; i < 4; ++i) {
            int t = t0 + wv * 16 + (l >> 4) * 4 + i;
            Pp[(size_t)t * NEXP + et * 16 + (l & 15)] = acc[et][i];
        }
    }
}

// ---------- kernel 2: reduce slices + softmax + argmax + bincount ------------
__global__ __launch_bounds__(256) void router_finish(
    const float* __restrict__ P, float* __restrict__ out, int S)
{
    const int lane = threadIdx.x & 63;   // expert
    const int wv   = threadIdx.x >> 6;
    const int t    = blockIdx.x * 4 + wv;

    float lg = 0.f;
    for (int s = 0; s < S; ++s)
        lg += P[((size_t)s * T_TOKENS + t) * NEXP + lane];

    float* out_w = out;
    float* out_i = out + T_TOKENS;
    float* out_s = out + 2 * T_TOKENS;
    float* out_c = out + 2 * T_TOKENS + (size_t)T_TOKENS * NEXP;

    float m = lg;
#pragma unroll
    for (int off = 32; off > 0; off >>= 1)
        m = fmaxf(m, __shfl_xor(m, off));
    float p = expf(lg - m);
    float s = p;
#pragma unroll
    for (int off = 32; off > 0; off >>= 1)
        s += __shfl_xor(s, off);
    float sc = p / s;

    float bv = sc; int bi = lane;
#pragma unroll
    for (int off = 32; off > 0; off >>= 1) {
        float ov = __shfl_xor(bv, off);
        int   oi = __shfl_xor(bi, off);
        if (ov > bv || (ov == bv && oi < bi)) { bv = ov; bi = oi; }
    }
    out_s[(size_t)t * NEXP + lane] = sc;
    if (lane == 0) {
        out_w[t] = bv;
        out_i[t] = (float)bi;
        atomicAdd(&out_c[bi], 1.0f);
    }
}

extern "C" void kernel_launch(void* const* d_in, const int* in_sizes, int n_in,
                              void* d_out, int out_size, void* d_ws, size_t ws_size,
                              hipStream_t stream)
{
    const float* x = (const float*)d_in[0];
    const float* W = (const float*)d_in[1];
    float* out = (float*)d_out;
    float* out_s = out + 2 * T_TOKENS;

    const size_t wf_bytes  = (size_t)128 * 4 * 3 * 64 * 16;          // 1.5 MiB
    const size_t per_slice = (size_t)T_TOKENS * NEXP * sizeof(float); // 2 MiB

    int S = 8;
    while (S > 1 && wf_bytes + (size_t)S * per_slice > ws_size) S >>= 1;
    float4* Wf = (float4*)d_ws;
    float* Pbuf;
    if (wf_bytes + per_slice <= ws_size) {
        Pbuf = (float*)((char*)d_ws + wf_bytes);
    } else {
        S = 1;
        Pbuf = out_s;   // single slice written straight into scores region
    }

    hipMemsetAsync(out + 2 * T_TOKENS + (size_t)T_TOKENS * NEXP, 0,
                   NEXP * sizeof(float), stream);

    wpack<<<dim3(128, 4), 64, 0, stream>>>(W, Wf);
    gemm_mfma<<<dim3(T_TOKENS / TB, S), 512, 0, stream>>>(x, Wf, Pbuf, K_DIM / S);
    router_finish<<<T_TOKENS / 4, 256, 0, stream>>>(Pbuf, out, S);
}